// Round 9
// baseline (331.698 us; speedup 1.0000x reference)
//
#include <hip/hip_runtime.h>

#define NPTS   8192
#define CCH    32
#define LDIM   64
#define ODIM   128
#define KNN    16
#define QPB    64                  // queries per scan block (4 waves x 16)
#define NCHK   4                   // candidate chunks
#define CHT    32                  // tiles per chunk (64 cands each)
#define SCAPC  48                  // survivor capacity per query per chunk
#define MARGIN 0.75f               // >= 2*eps bound for fp16 distance error

typedef _Float16 half8   __attribute__((ext_vector_type(8)));
typedef float    float4v __attribute__((ext_vector_type(4)));

// CANDIDATE-SPLIT 2-KERNEL SCHEME (R8 post-mortem): total wave count was the
// bottleneck -- 32768 queries / 16-per-wave = 2048 waves = 8 waves/CU, grid-
// capped in every single-kernel variant (R2=251us, R8 no-barrier=238us,
// R6 16w/CU=195us: residency, not structure, is the lever). Splitting the
// candidate axis across blocks gives 512 qgroups x 4 chunks = 2048 blocks =
// 32 waves/CU + backfill. scan_kernel: R6's proven 44-VGPR scan loop on a
// 2048-cand chunk; chunk-local threshold (16-col top-2 union, same MARGIN
// bound); u16 survivors; exact fp32 keys; writes chunk-exact top-16 (any
// global top-16 elem is in its chunk's top-16 => union of 4x16 covers it).
// finish_kernel: recompute exact keys for the 64 union cands (same arithmetic
// as the verified pass-3), lex rank-select top-16, then the proven epilogue.
//
// scan LDS (18944 B -> 8 blocks/CU, 151.5 KB):
//   region0 @0 (12288): stage bufs 2x4352 / t32 overlay (64*33*4=8448, after
//     pass-1, dead before pass-2 stage(0)) / skeys overlay (64*48*4=12288,
//     pass-3, bufs dead)
//   slist u16 @12288 (64*48*2=6144) | scnt @18432 (256) | tq @18688 (256)
#define LDSA 18944
#define A_SL 12288
#define A_SC 18432
#define A_TQ 18688

__device__ __forceinline__ void gload_lds16(const void* g, void* l) {
    __builtin_amdgcn_global_load_lds(
        (const __attribute__((address_space(1))) unsigned int*)g,
        (__attribute__((address_space(3))) unsigned int*)l, 16, 0, 0);
}
__device__ __forceinline__ void gload_lds4(const void* g, void* l) {
    __builtin_amdgcn_global_load_lds(
        (const __attribute__((address_space(1))) unsigned int*)g,
        (__attribute__((address_space(3))) unsigned int*)l, 4, 0, 0);
}

// Prologue: fp32 squared norms (same summation order -> identical bits) and
// fp16 candidates in B-fragment order for 64-cand tiles:
//   point p: frag byte addr = (p>>6)*4096 + ((p>>4)&3)*1024 + quad*256 + (p&15)*16
__global__ void prep_kernel(const float* __restrict__ x, float* __restrict__ sqg,
                            _Float16* __restrict__ xh) {
    int p = blockIdx.x * 256 + threadIdx.x;      // 0..32767
    const float4* src = (const float4*)(x + (size_t)p * CCH);
    float4 f[8];
    #pragma unroll
    for (int k = 0; k < 8; ++k) f[k] = src[k];
    float s = 0.f;
    #pragma unroll
    for (int k = 0; k < 8; ++k)
        s += f[k].x * f[k].x + f[k].y * f[k].y + f[k].z * f[k].z + f[k].w * f[k].w;
    sqg[p] = s;
    half8* dst = (half8*)xh + ((p >> 6) * 256 + ((p >> 4) & 3) * 64 + (p & 15));
    #pragma unroll
    for (int q = 0; q < 4; ++q) {
        float4 a = f[2 * q], c = f[2 * q + 1];
        half8 h;
        h[0] = (_Float16)a.x; h[1] = (_Float16)a.y; h[2] = (_Float16)a.z; h[3] = (_Float16)a.w;
        h[4] = (_Float16)c.x; h[5] = (_Float16)c.y; h[6] = (_Float16)c.z; h[7] = (_Float16)c.w;
        dst[q * 16] = h;                          // quad stride = 16 half8 = 256B
    }
}

__global__ __launch_bounds__(256, 8)
void scan_kernel(const float* __restrict__ x,
                 const float* __restrict__ sqg,
                 const char* __restrict__ xh,
                 unsigned short* __restrict__ cand)
{
    __shared__ __align__(16) char smem[LDSA];
    float*          t32   = (float*)smem;                       // overlay
    float*          skeys = (float*)smem;                       // overlay
    unsigned short* slist = (unsigned short*)(smem + A_SL);
    int*            scnt  = (int*)(smem + A_SC);
    float*          tq    = (float*)(smem + A_TQ);

    const int tid  = threadIdx.x;
    const int lane = tid & 63;
    const int w    = tid >> 6;                 // 0..3
    const int col  = lane & 15;
    const int quad = lane >> 4;
    const float INF = __builtin_inff();

    const int chunk = blockIdx.x & (NCHK - 1);
    const int qgi   = blockIdx.x >> 2;
    const int qb0   = qgi * QPB;               // global query base
    const int b     = qb0 >> 13;
    const int qbl   = qb0 & (NPTS - 1);
    const int S     = qgi & (CHT - 1);         // tile-order stagger
    const float* xb  = x   + (size_t)(b << 13) * CCH;
    const float* sqb = sqg + (b << 13);
    const char*  xhb = xh + (size_t)b * 128 * 4096;

    // A-fragment: wave's 16 queries, A[m=col][k=quad*8+j]
    half8 qh;
    {
        int p = qb0 + w * 16 + col;
        qh = *(const half8*)(xh + (size_t)(p >> 6) * 4096 + ((p >> 4) & 3) * 1024
                             + quad * 256 + (p & 15) * 16);
    }

    auto stage = [&](int I) {                  // 4KB frag + 256B sq per tile
        char* sb = smem + ((I & 1) ? 4352 : 0);
        int t = chunk * CHT + ((I + S) & (CHT - 1));
        const char* src = xhb + (size_t)t * 4096;
        gload_lds16(src + tid * 16, sb + w * 1024);   // lds = base + lane*16
        if (w == 0) gload_lds4(sqb + t * 64 + lane, sb + 4096);
    };

    // ===== PASS 1: per-lane top-2 per query over the chunk =====
    float m1[4] = {INF, INF, INF, INF};
    float m2[4] = {INF, INF, INF, INF};
    stage(0);
    __syncthreads();
    #pragma unroll 1
    for (int I = 0; I < CHT; ++I) {
        if (I + 1 < CHT) stage(I + 1);
        const char*  cb = smem + ((I & 1) ? 4352 : 0);
        const float* sv = (const float*)(cb + 4096);
        #pragma unroll
        for (int st = 0; st < 4; ++st) {
            half8 bh = *(const half8*)(cb + st * 1024 + lane * 16);
            float sc = sv[st * 16 + col];
            float4v acc = __builtin_amdgcn_mfma_f32_16x16x32_f16(
                qh, bh, (float4v){0.f, 0.f, 0.f, 0.f}, 0, 0, 0);
            #pragma unroll
            for (int j = 0; j < 4; ++j) {
                float key = fmaf(-2.f, acc[j], sc);
                float o1  = m1[j];
                m1[j] = fminf(key, o1);
                m2[j] = __builtin_amdgcn_fmed3f(key, o1, m2[j]);
            }
        }
        __syncthreads();
    }

    // ===== chunk-local threshold: 16th smallest of 16-col x top-2 = 32 =====
    #pragma unroll
    for (int j = 0; j < 4; ++j) {
        int qq = w * 16 + quad * 4 + j;
        t32[qq * 33 + col * 2 + 0] = m1[j];
        t32[qq * 33 + col * 2 + 1] = m2[j];
    }
    __syncthreads();
    {
        int q = tid & 63, wt = tid >> 6;       // 4 workers x 8 items
        float v[8]; int r[8];
        #pragma unroll
        for (int u = 0; u < 8; ++u) { v[u] = t32[q * 33 + wt * 8 + u]; r[u] = 0; }
        #pragma unroll 8
        for (int jj = 0; jj < 32; ++jj) {
            float vj = t32[q * 33 + jj];
            #pragma unroll
            for (int u = 0; u < 8; ++u)
                r[u] += (int)(vj < v[u]) | ((int)(vj == v[u]) & (int)(jj < wt * 8 + u));
        }
        #pragma unroll
        for (int u = 0; u < 8; ++u)
            if (r[u] == KNN - 1) tq[q] = v[u];
        if (tid < QPB) scnt[tid] = 0;
    }
    __syncthreads();
    float T2[4];
    #pragma unroll
    for (int j = 0; j < 4; ++j) T2[j] = tq[w * 16 + quad * 4 + j] + MARGIN;

    // ===== PASS 2: rescan chunk, append survivors (u16) =====
    stage(0);
    __syncthreads();
    #pragma unroll 1
    for (int I = 0; I < CHT; ++I) {
        if (I + 1 < CHT) stage(I + 1);
        const char*  cb = smem + ((I & 1) ? 4352 : 0);
        const float* sv = (const float*)(cb + 4096);
        int tbase = (chunk * CHT + ((I + S) & (CHT - 1))) * 64;
        #pragma unroll
        for (int st = 0; st < 4; ++st) {
            half8 bh = *(const half8*)(cb + st * 1024 + lane * 16);
            float sc = sv[st * 16 + col];
            float4v acc = __builtin_amdgcn_mfma_f32_16x16x32_f16(
                qh, bh, (float4v){0.f, 0.f, 0.f, 0.f}, 0, 0, 0);
            #pragma unroll
            for (int j = 0; j < 4; ++j) {
                float key = fmaf(-2.f, acc[j], sc);
                if (key < T2[j]) {
                    int qq = w * 16 + quad * 4 + j;
                    int slot = atomicAdd(&scnt[qq], 1);
                    if (slot < SCAPC)
                        slist[qq * SCAPC + slot] =
                            (unsigned short)(tbase + st * 16 + col);
                }
            }
        }
        __syncthreads();
    }

    // ===== PASS 3: exact fp32 keys for survivors =====
    {
        int q = tid & 63, wt = tid >> 6;
        int n = scnt[q]; if (n > SCAPC) n = SCAPC;
        const float4* xi4 = (const float4*)(xb + (size_t)(qbl + q) * CCH);
        for (int s = wt; s < n; s += 4) {
            int jdx = slist[q * SCAPC + s];
            const float4* xj = (const float4*)(xb + (size_t)jdx * CCH);
            float a0 = 0.f, a1 = 0.f, a2 = 0.f, a3 = 0.f;
            #pragma unroll 2
            for (int k = 0; k < 8; ++k) {
                float4 cv = xj[k], qv = xi4[k];
                a0 = fmaf(cv.x, qv.x, a0); a1 = fmaf(cv.y, qv.y, a1);
                a2 = fmaf(cv.z, qv.z, a2); a3 = fmaf(cv.w, qv.w, a3);
            }
            float dot = (a0 + a1) + (a2 + a3);
            skeys[q * SCAPC + s] = fmaf(-2.f, dot, sqb[jdx]);
        }
    }
    __syncthreads();
    // ===== chunk-exact top-16 via rank (lex on (key, idx)) -> global u16 =====
    // n >= 16 guaranteed (the 16 approx-smallest all pass T+MARGIN).
    {
        int q = tid & 63, wt = tid >> 6;
        int n = scnt[q]; if (n > SCAPC) n = SCAPC;
        unsigned short* dst = cand + ((size_t)(qb0 + q) * NCHK + chunk) * KNN;
        for (int s = wt; s < n; s += 4) {
            float k = skeys[q * SCAPC + s];
            int   i = slist[q * SCAPC + s];
            int rank = 0;
            #pragma unroll 4
            for (int jj = 0; jj < n; ++jj) {
                float kj = skeys[q * SCAPC + jj];
                int   ij = slist[q * SCAPC + jj];
                rank += (int)(kj < k) | ((int)(kj == k) & (int)(ij < i));
            }
            if (rank < KNN) dst[rank] = (unsigned short)i;
        }
    }
}

// finish: 32 queries/block, 1024 blocks. Merge 4x16 chunk candidates by
// recomputed exact keys (same arithmetic as scan pass-3), then epilogue.
// LDS: midx u16 @0 (32*64*2=4096) | mkeys @4096 (32*65*4=8320 -> 12416)
//      kn @12544 (2048 -> 14592) | epilogue: pl @0 (32*33*4=4224) |
//      hh @4224 (32*65*4=8320 -> 12544, disjoint from kn)
#define LDSB 14592
__global__ __launch_bounds__(256, 4)
void finish_kernel(const float* __restrict__ x,
                   const float* __restrict__ sqg,
                   const unsigned short* __restrict__ cand,
                   const float* __restrict__ Wl,
                   const float* __restrict__ bl,
                   const float* __restrict__ Wc,
                   const float* __restrict__ bc,
                   float* __restrict__ out)
{
    __shared__ __align__(16) char smem[LDSB];
    unsigned short* midx  = (unsigned short*)smem;
    float*          mkeys = (float*)(smem + 4096);
    int*            kn    = (int*)(smem + 12544);
    float*          pl    = (float*)smem;          // epilogue overlays
    float*          hh    = (float*)(smem + 4224);

    const int tid = threadIdx.x;
    const int b   = blockIdx.x >> 8;               // 256 qgroups per batch
    const int qbl = (blockIdx.x & 255) * 32;
    const int qb0 = (b << 13) + qbl;
    const float* xb  = x   + (size_t)(b << 13) * CCH;
    const float* sqb = sqg + (b << 13);
    const float INF = __builtin_inff();

    // load 32 queries x 64 candidate u16 (coalesced)
    {
        const uint4* src = (const uint4*)(cand + (size_t)qb0 * 64);
        ((uint4*)midx)[tid] = src[tid];            // 256 x 16B = 4096B
    }
    __syncthreads();
    // exact keys for all 64 union candidates (same arithmetic as scan pass-3)
    {
        int q = tid >> 3, wt = tid & 7;            // 8 workers per query
        const float4* xi4 = (const float4*)(xb + (size_t)(qbl + q) * CCH);
        for (int c = wt; c < 64; c += 8) {
            int jdx = midx[q * 64 + c];
            const float4* xj = (const float4*)(xb + (size_t)jdx * CCH);
            float a0 = 0.f, a1 = 0.f, a2 = 0.f, a3 = 0.f;
            #pragma unroll 2
            for (int k = 0; k < 8; ++k) {
                float4 cv = xj[k], qv = xi4[k];
                a0 = fmaf(cv.x, qv.x, a0); a1 = fmaf(cv.y, qv.y, a1);
                a2 = fmaf(cv.z, qv.z, a2); a3 = fmaf(cv.w, qv.w, a3);
            }
            float dot = (a0 + a1) + (a2 + a3);
            mkeys[q * 65 + c] = fmaf(-2.f, dot, sqb[jdx]);
        }
    }
    __syncthreads();
    // global top-16 via rank over the 64 union cands (chunks disjoint -> idx unique)
    {
        int q = tid >> 3, wt = tid & 7;
        for (int c = wt; c < 64; c += 8) {
            float k = mkeys[q * 65 + c];
            int   i = midx[q * 64 + c];
            int rank = 0;
            #pragma unroll 4
            for (int jj = 0; jj < 64; ++jj) {
                float kj = mkeys[q * 65 + jj];
                int   ij = midx[q * 64 + jj];
                rank += (int)(kj < k) | ((int)(kj == k) & (int)(ij < i));
            }
            if (rank < KNN) kn[q * KNN + rank] = i;
        }
    }
    __syncthreads();
    // gather + max-pool
    {
        int q = tid >> 3, part = tid & 7;          // 8 threads/query, one float4
        float4 m0 = make_float4(-INF, -INF, -INF, -INF);
        #pragma unroll 4
        for (int k = 0; k < KNN; ++k) {
            int j = kn[q * KNN + k];
            float4 v = *(const float4*)(xb + (size_t)j * CCH + part * 4);
            m0.x = fmaxf(m0.x, v.x); m0.y = fmaxf(m0.y, v.y);
            m0.z = fmaxf(m0.z, v.z); m0.w = fmaxf(m0.w, v.w);
        }
        float* d = pl + q * 33 + part * 4;
        d[0] = m0.x; d[1] = m0.y; d[2] = m0.z; d[3] = m0.w;
    }
    __syncthreads();
    {
        int l = tid & 63, qg2 = tid >> 6;          // 4 query-slices
        #pragma unroll 1
        for (int qq = qg2; qq < 32; qq += 4) {
            float acc = bl[l];
            #pragma unroll 8
            for (int c = 0; c < CCH; ++c)
                acc = fmaf(pl[qq * 33 + c], Wl[c * LDIM + l], acc);
            hh[qq * 65 + l] = acc;
        }
    }
    __syncthreads();
    {
        int o = tid & 127, qh2 = tid >> 7;         // 2 query-slices
        #pragma unroll 1
        for (int qq = qh2; qq < 32; qq += 2) {
            float acc = bc[o];
            #pragma unroll 8
            for (int l = 0; l < LDIM; ++l)
                acc = fmaf(hh[qq * 65 + l], Wc[l * ODIM + o], acc);
            out[(size_t)(qb0 + qq) * ODIM + o] = fmaxf(acc, 0.f);
        }
    }
}

extern "C" void kernel_launch(void* const* d_in, const int* in_sizes, int n_in,
                              void* d_out, int out_size, void* d_ws, size_t ws_size,
                              hipStream_t stream) {
    const float* x  = (const float*)d_in[0];
    const float* Wl = (const float*)d_in[1];
    const float* bl = (const float*)d_in[2];
    const float* Wc = (const float*)d_in[3];
    const float* bc = (const float*)d_in[4];
    float* out = (float*)d_out;
    float*          sqf = (float*)d_ws;                          // 128 KB
    _Float16*       xh  = (_Float16*)((char*)d_ws + 131072);     // 2 MB frag-order
    unsigned short* cnd = (unsigned short*)((char*)d_ws + 131072 + 2097152); // 4 MB
    (void)in_sizes; (void)n_in; (void)out_size; (void)ws_size;

    hipLaunchKernelGGL(prep_kernel, dim3((4 * NPTS) / 256), dim3(256), 0, stream,
                       x, sqf, xh);
    hipLaunchKernelGGL(scan_kernel, dim3((32768 / QPB) * NCHK), dim3(256), 0, stream,
                       x, sqf, (const char*)xh, cnd);
    hipLaunchKernelGGL(finish_kernel, dim3(1024), dim3(256), 0, stream,
                       x, sqf, cnd, Wl, bl, Wc, bc, out);
}

// Round 10
// 313.095 us; speedup vs baseline: 1.0594x; 1.0594x over previous
//
#include <hip/hip_runtime.h>

#define NPTS   8192
#define CCH    32
#define LDIM   64
#define ODIM   128
#define KNN    16
#define QPB    64                  // queries per scan block (4 waves x 16)
#define NCHK   4                   // candidate chunks
#define CHT    32                  // tiles per chunk (64 cands each)
#define SCAPC  50                  // survivor cap/query/chunk (R9: <=48 empirically); u16 word-stride 25 (odd) -> conflict-free
#define SKSTR  51                  // skeys row stride (odd) -> conflict-free
#define MARGIN 0.75f               // >= 2*eps bound for fp16 distance error (fp32 ULP noise << this)

typedef _Float16 half8   __attribute__((ext_vector_type(8)));
typedef float    float4v __attribute__((ext_vector_type(4)));

// R9 post-mortem: occupancy 70% but scan still 190us -- __syncthreads() drains
// vmcnt(0) on the just-issued prefetch EVERY tile (64x full load latency,
// issue-work is only ~26us/SIMD). Fix = counted-vmcnt pipeline (T4/m201):
// 3 LDS buffers, stage(I+2) per iter, asm vmcnt(2) + raw s_barrier +
// sched_barrier(0). Every wave issues exactly 2 loads/stage (sq row loaded
// redundantly by all 4 waves -- identical data, uniform vmcnt). Loads live
// across 2 iterations; never drained to 0 inside the loop.
// Also: A-frag prescaled by -2 (exact) + MFMA C preloaded with sq[cand]
// (R8-verified) -> key = acc[j], inner loop 2 VALU/cell. Selection strides
// made odd (R9's slist stride-48 u16 was a 16-way conflict -> 1.02e7 cycles).
// Scan emits exact chunk top-16 (key f32 + idx u16); finish merges 4x16
// precomputed keys (no re-gather/dot recompute) + verified epilogue.
//
// scan LDS (19968 B -> 8 blocks/CU, 156 KB):
//   bufs 3x4352 @0 (13056) | t32 overlay @0 (64*33*4=8448) | skeys overlay @0
//   (64*51*4=13056) | slist u16 @13056 (64*50*2=6400) | scnt @19456 (256) |
//   tq @19712 (256)
#define LDSA 19968
#define A_SL 13056
#define A_SC 19456
#define A_TQ 19712

__device__ __forceinline__ void gload_lds16(const void* g, void* l) {
    __builtin_amdgcn_global_load_lds(
        (const __attribute__((address_space(1))) unsigned int*)g,
        (__attribute__((address_space(3))) unsigned int*)l, 16, 0, 0);
}
__device__ __forceinline__ void gload_lds4(const void* g, void* l) {
    __builtin_amdgcn_global_load_lds(
        (const __attribute__((address_space(1))) unsigned int*)g,
        (__attribute__((address_space(3))) unsigned int*)l, 4, 0, 0);
}

// Prologue: fp32 squared norms (same summation order -> identical bits) and
// fp16 candidates in B-fragment order for 64-cand tiles:
//   point p: frag byte addr = (p>>6)*4096 + ((p>>4)&3)*1024 + quad*256 + (p&15)*16
__global__ void prep_kernel(const float* __restrict__ x, float* __restrict__ sqg,
                            _Float16* __restrict__ xh) {
    int p = blockIdx.x * 256 + threadIdx.x;      // 0..32767
    const float4* src = (const float4*)(x + (size_t)p * CCH);
    float4 f[8];
    #pragma unroll
    for (int k = 0; k < 8; ++k) f[k] = src[k];
    float s = 0.f;
    #pragma unroll
    for (int k = 0; k < 8; ++k)
        s += f[k].x * f[k].x + f[k].y * f[k].y + f[k].z * f[k].z + f[k].w * f[k].w;
    sqg[p] = s;
    half8* dst = (half8*)xh + ((p >> 6) * 256 + ((p >> 4) & 3) * 64 + (p & 15));
    #pragma unroll
    for (int q = 0; q < 4; ++q) {
        float4 a = f[2 * q], c = f[2 * q + 1];
        half8 h;
        h[0] = (_Float16)a.x; h[1] = (_Float16)a.y; h[2] = (_Float16)a.z; h[3] = (_Float16)a.w;
        h[4] = (_Float16)c.x; h[5] = (_Float16)c.y; h[6] = (_Float16)c.z; h[7] = (_Float16)c.w;
        dst[q * 16] = h;                          // quad stride = 16 half8 = 256B
    }
}

__global__ __launch_bounds__(256, 8)
void scan_kernel(const float* __restrict__ x,
                 const float* __restrict__ sqg,
                 const char* __restrict__ xh,
                 float* __restrict__ kbuf,
                 unsigned short* __restrict__ ibuf)
{
    __shared__ __align__(16) char smem[LDSA];
    float*          t32   = (float*)smem;                       // overlay
    float*          skeys = (float*)smem;                       // overlay
    unsigned short* slist = (unsigned short*)(smem + A_SL);
    int*            scnt  = (int*)(smem + A_SC);
    float*          tq    = (float*)(smem + A_TQ);

    const int tid  = threadIdx.x;
    const int lane = tid & 63;
    const int w    = tid >> 6;                 // 0..3
    const int col  = lane & 15;
    const int quad = lane >> 4;
    const float INF = __builtin_inff();

    const int chunk = blockIdx.x & (NCHK - 1);
    const int qgi   = blockIdx.x >> 2;
    const int qb0   = qgi * QPB;
    const int b     = qb0 >> 13;
    const int qbl   = qb0 & (NPTS - 1);
    const int S     = qgi & (CHT - 1);         // tile-order stagger
    const float* xb  = x   + (size_t)(b << 13) * CCH;
    const float* sqb = sqg + (b << 13);
    const char*  xhb = xh + (size_t)b * 128 * 4096;

    // A-fragment prescaled by -2 (exact): MFMA(C=sq[c]) output IS the key
    half8 qh;
    {
        int p = qb0 + w * 16 + col;
        qh = *(const half8*)(xh + (size_t)(p >> 6) * 4096 + ((p >> 4) & 3) * 1024
                             + quad * 256 + (p & 15) * 16);
        #pragma unroll
        for (int i = 0; i < 8; ++i) qh[i] = qh[i] * (_Float16)-2.0f;
    }
    // retire qh so the pipeline's vmcnt counts are exact from here on
    asm volatile("s_waitcnt vmcnt(0)" ::: "memory");

    // stage: EXACTLY 2 VMEM per wave (frag chunk + redundant identical sq row)
    auto stageto = [&](char* sb, int I) {
        int t = chunk * CHT + ((I + S) & (CHT - 1));
        const char* src = xhb + (size_t)t * 4096;
        gload_lds16(src + tid * 16, sb + w * 1024);     // lds = base + lane*16
        gload_lds4(sqb + t * 64 + lane, sb + 4096);     // all 4 waves, same data
    };

    // ===== PASS 1: per-lane top-2 per query, counted-vmcnt pipeline =====
    float m1[4] = {INF, INF, INF, INF};
    float m2[4] = {INF, INF, INF, INF};
    {
        char *p0 = smem, *p1 = smem + 4352, *p2 = smem + 8704;
        stageto(p0, 0); stageto(p1, 1);
        #pragma unroll 1
        for (int I = 0; I < CHT; ++I) {
            // outstanding: stage(I)=2, stage(I+1)=2 -> wait oldest 2, keep 2
            asm volatile("s_waitcnt vmcnt(2)" ::: "memory");
            __builtin_amdgcn_s_barrier();          // tile I visible; I-1 reads done
            __builtin_amdgcn_sched_barrier(0);
            stageto(p2, I + 2);                    // wraps past end: harmless
            const float* sv = (const float*)(p0 + 4096);
            #pragma unroll
            for (int st = 0; st < 4; ++st) {
                half8 bh = *(const half8*)(p0 + st * 1024 + lane * 16);
                float sc = sv[st * 16 + col];
                float4v acc = __builtin_amdgcn_mfma_f32_16x16x32_f16(
                    qh, bh, (float4v){sc, sc, sc, sc}, 0, 0, 0);
                #pragma unroll
                for (int j = 0; j < 4; ++j) {
                    float key = acc[j], o1 = m1[j];
                    m1[j] = fminf(key, o1);
                    m2[j] = __builtin_amdgcn_fmed3f(key, o1, m2[j]);
                }
            }
            char* t_ = p0; p0 = p1; p1 = p2; p2 = t_;
        }
    }
    __syncthreads();   // full drain (wrapped stages in flight) before t32 overlay

    // ===== chunk-local threshold: 16th smallest of 16-col x top-2 = 32 =====
    #pragma unroll
    for (int j = 0; j < 4; ++j) {
        int qq = w * 16 + quad * 4 + j;
        t32[qq * 33 + col * 2 + 0] = m1[j];
        t32[qq * 33 + col * 2 + 1] = m2[j];
    }
    __syncthreads();
    {
        int q = tid & 63, wt = tid >> 6;       // 4 workers x 8 items
        float v[8]; int r[8];
        #pragma unroll
        for (int u = 0; u < 8; ++u) { v[u] = t32[q * 33 + wt * 8 + u]; r[u] = 0; }
        #pragma unroll 8
        for (int jj = 0; jj < 32; ++jj) {
            float vj = t32[q * 33 + jj];
            #pragma unroll
            for (int u = 0; u < 8; ++u)
                r[u] += (int)(vj < v[u]) | ((int)(vj == v[u]) & (int)(jj < wt * 8 + u));
        }
        #pragma unroll
        for (int u = 0; u < 8; ++u)
            if (r[u] == KNN - 1) tq[q] = v[u];
        if (tid < QPB) scnt[tid] = 0;
    }
    __syncthreads();
    float T2[4];
    #pragma unroll
    for (int j = 0; j < 4; ++j) T2[j] = tq[w * 16 + quad * 4 + j] + MARGIN;

    // ===== PASS 2: rescan, append survivors (u16), same pipeline =====
    {
        char *p0 = smem, *p1 = smem + 4352, *p2 = smem + 8704;
        stageto(p0, 0); stageto(p1, 1);
        #pragma unroll 1
        for (int I = 0; I < CHT; ++I) {
            asm volatile("s_waitcnt vmcnt(2)" ::: "memory");
            __builtin_amdgcn_s_barrier();
            __builtin_amdgcn_sched_barrier(0);
            stageto(p2, I + 2);
            const float* sv = (const float*)(p0 + 4096);
            int tbase = (chunk * CHT + ((I + S) & (CHT - 1))) * 64;
            #pragma unroll
            for (int st = 0; st < 4; ++st) {
                half8 bh = *(const half8*)(p0 + st * 1024 + lane * 16);
                float sc = sv[st * 16 + col];
                float4v acc = __builtin_amdgcn_mfma_f32_16x16x32_f16(
                    qh, bh, (float4v){sc, sc, sc, sc}, 0, 0, 0);
                #pragma unroll
                for (int j = 0; j < 4; ++j) {
                    float key = acc[j];
                    if (key < T2[j]) {
                        int qq = w * 16 + quad * 4 + j;
                        int slot = atomicAdd(&scnt[qq], 1);
                        if (slot < SCAPC)
                            slist[qq * SCAPC + slot] =
                                (unsigned short)(tbase + st * 16 + col);
                    }
                }
            }
            char* t_ = p0; p0 = p1; p1 = p2; p2 = t_;
        }
    }
    __syncthreads();   // drain before skeys overlay

    // ===== PASS 3: exact fp32 keys for survivors =====
    {
        int q = tid & 63, wt = tid >> 6;
        int n = scnt[q]; if (n > SCAPC) n = SCAPC;
        const float4* xi4 = (const float4*)(xb + (size_t)(qbl + q) * CCH);
        for (int s = wt; s < n; s += 4) {
            int jdx = slist[q * SCAPC + s];
            const float4* xj = (const float4*)(xb + (size_t)jdx * CCH);
            float a0 = 0.f, a1 = 0.f, a2 = 0.f, a3 = 0.f;
            #pragma unroll 2
            for (int k = 0; k < 8; ++k) {
                float4 cv = xj[k], qv = xi4[k];
                a0 = fmaf(cv.x, qv.x, a0); a1 = fmaf(cv.y, qv.y, a1);
                a2 = fmaf(cv.z, qv.z, a2); a3 = fmaf(cv.w, qv.w, a3);
            }
            float dot = (a0 + a1) + (a2 + a3);
            skeys[q * SKSTR + s] = fmaf(-2.f, dot, sqb[jdx]);
        }
    }
    __syncthreads();
    // ===== chunk-exact top-16 via rank -> global (key f32, idx u16) =====
    {
        int q = tid & 63, wt = tid >> 6;
        int n = scnt[q]; if (n > SCAPC) n = SCAPC;
        float*          kdst = kbuf + (size_t)(qb0 + q) * 64 + chunk * KNN;
        unsigned short* idst = ibuf + (size_t)(qb0 + q) * 64 + chunk * KNN;
        for (int s = wt; s < n; s += 4) {
            float k = skeys[q * SKSTR + s];
            int   i = slist[q * SCAPC + s];
            int rank = 0;
            #pragma unroll 4
            for (int jj = 0; jj < n; ++jj) {
                float kj = skeys[q * SKSTR + jj];
                int   ij = slist[q * SCAPC + jj];
                rank += (int)(kj < k) | ((int)(kj == k) & (int)(ij < i));
            }
            if (rank < KNN) { kdst[rank] = k; idst[rank] = (unsigned short)i; }
        }
    }
}

// finish: 32 q/block, 1024 blocks. Merge 4x16 precomputed exact (key,idx) by
// lex rank (chunks disjoint -> unique idx), then verified epilogue.
// LDS: mkeys [32][65] @0 (8320) | midx u16 [32][72] @8320 (4608 -> 12928)
//      kn @12928 (2048 -> 14976) | epilogue pl @0 (4224) | hh @4224 (8320 -> 12544)
#define LDSB 14976
__global__ __launch_bounds__(256, 4)
void finish_kernel(const float* __restrict__ x,
                   const float* __restrict__ kbuf,
                   const unsigned short* __restrict__ ibuf,
                   const float* __restrict__ Wl,
                   const float* __restrict__ bl,
                   const float* __restrict__ Wc,
                   const float* __restrict__ bc,
                   float* __restrict__ out)
{
    __shared__ __align__(16) char smem[LDSB];
    float*          mkeys = (float*)smem;
    unsigned short* midx  = (unsigned short*)(smem + 8320);
    int*            kn    = (int*)(smem + 12928);
    float*          pl    = (float*)smem;          // epilogue overlays
    float*          hh    = (float*)(smem + 4224);

    const int tid = threadIdx.x;
    const int b   = blockIdx.x >> 8;               // 256 qgroups per batch
    const int qbl = (blockIdx.x & 255) * 32;
    const int qb0 = (b << 13) + qbl;
    const float* xb = x + (size_t)(b << 13) * CCH;
    const float INF = __builtin_inff();

    // coalesced load of 64 keys + 64 idx per query
    {
        int q = tid >> 3, c8 = (tid & 7) * 8;
        const float4* ks = (const float4*)(kbuf + (size_t)(qb0 + q) * 64 + c8);
        float4 k0 = ks[0], k1 = ks[1];
        uint4 iv = *(const uint4*)(ibuf + (size_t)(qb0 + q) * 64 + c8);
        float* kd = mkeys + q * 65 + c8;
        kd[0] = k0.x; kd[1] = k0.y; kd[2] = k0.z; kd[3] = k0.w;
        kd[4] = k1.x; kd[5] = k1.y; kd[6] = k1.z; kd[7] = k1.w;
        *(uint4*)(midx + q * 72 + c8) = iv;        // 16B-aligned (144B rows)
    }
    __syncthreads();
    // global top-16 via rank over the 64 union candidates
    {
        int q = tid >> 3, wt = tid & 7;
        for (int c = wt; c < 64; c += 8) {
            float k = mkeys[q * 65 + c];
            int   i = midx[q * 72 + c];
            int rank = 0;
            #pragma unroll 4
            for (int jj = 0; jj < 64; ++jj) {
                float kj = mkeys[q * 65 + jj];
                int   ij = midx[q * 72 + jj];
                rank += (int)(kj < k) | ((int)(kj == k) & (int)(ij < i));
            }
            if (rank < KNN) kn[q * KNN + rank] = i;
        }
    }
    __syncthreads();
    // gather + max-pool
    {
        int q = tid >> 3, part = tid & 7;          // 8 threads/query, one float4
        float4 m0 = make_float4(-INF, -INF, -INF, -INF);
        #pragma unroll 4
        for (int k = 0; k < KNN; ++k) {
            int j = kn[q * KNN + k];
            float4 v = *(const float4*)(xb + (size_t)j * CCH + part * 4);
            m0.x = fmaxf(m0.x, v.x); m0.y = fmaxf(m0.y, v.y);
            m0.z = fmaxf(m0.z, v.z); m0.w = fmaxf(m0.w, v.w);
        }
        float* d = pl + q * 33 + part * 4;
        d[0] = m0.x; d[1] = m0.y; d[2] = m0.z; d[3] = m0.w;
    }
    __syncthreads();
    {
        int l = tid & 63, qg2 = tid >> 6;          // 4 query-slices
        #pragma unroll 1
        for (int qq = qg2; qq < 32; qq += 4) {
            float acc = bl[l];
            #pragma unroll 8
            for (int c = 0; c < CCH; ++c)
                acc = fmaf(pl[qq * 33 + c], Wl[c * LDIM + l], acc);
            hh[qq * 65 + l] = acc;
        }
    }
    __syncthreads();
    {
        int o = tid & 127, qh2 = tid >> 7;         // 2 query-slices
        #pragma unroll 1
        for (int qq = qh2; qq < 32; qq += 2) {
            float acc = bc[o];
            #pragma unroll 8
            for (int l = 0; l < LDIM; ++l)
                acc = fmaf(hh[qq * 65 + l], Wc[l * ODIM + o], acc);
            out[(size_t)(qb0 + qq) * ODIM + o] = fmaxf(acc, 0.f);
        }
    }
}

extern "C" void kernel_launch(void* const* d_in, const int* in_sizes, int n_in,
                              void* d_out, int out_size, void* d_ws, size_t ws_size,
                              hipStream_t stream) {
    const float* x  = (const float*)d_in[0];
    const float* Wl = (const float*)d_in[1];
    const float* bl = (const float*)d_in[2];
    const float* Wc = (const float*)d_in[3];
    const float* bc = (const float*)d_in[4];
    float* out = (float*)d_out;
    float*          sqf  = (float*)d_ws;                                   // 128 KB
    _Float16*       xh   = (_Float16*)((char*)d_ws + 131072);              // 2 MB
    float*          kbuf = (float*)((char*)d_ws + 2228224);                // 8 MB
    unsigned short* ibuf = (unsigned short*)((char*)d_ws + 10616832);      // 4 MB (total 14.7 MB)
    (void)in_sizes; (void)n_in; (void)out_size; (void)ws_size;

    hipLaunchKernelGGL(prep_kernel, dim3((4 * NPTS) / 256), dim3(256), 0, stream,
                       x, sqf, xh);
    hipLaunchKernelGGL(scan_kernel, dim3((32768 / QPB) * NCHK), dim3(256), 0, stream,
                       x, sqf, (const char*)xh, kbuf, ibuf);
    hipLaunchKernelGGL(finish_kernel, dim3(1024), dim3(256), 0, stream,
                       x, kbuf, ibuf, Wl, bl, Wc, bc, out);
}